// Round 1
// baseline (1048.572 us; speedup 1.0000x reference)
//
#include <hip/hip_runtime.h>
#include <math.h>

// Problem constants
#define BATCH 2
#define SEQ   2048
#define DMODEL 1024
#define NHEAD 16
#define HEADD 64
#define MROWS (BATCH * SEQ)   // 4096

// ---------------- Generic fp32 GEMM: C[M,N] = A[M,K] @ B[K,N] ----------------
// 64x64 block tile, BK=16, 256 threads, 4x4 register tile per thread.
#define BM 64
#define BN 64
#define BK 16
#define LDA 68   // padded leading dim for transposed A tile (float4-aligned)

__global__ __launch_bounds__(256) void gemm_f32(const float* __restrict__ A,
                                                const float* __restrict__ B,
                                                float* __restrict__ C,
                                                int M, int N, int K) {
    __shared__ float As[BK * LDA];  // [k][m] transposed
    __shared__ float Bs[BK * BN];   // [k][n]

    const int tid = threadIdx.x;
    const int tx = tid & 15;        // 0..15  (n dir)
    const int ty = tid >> 4;        // 0..15  (m dir)
    const int bm = blockIdx.y * BM;
    const int bn = blockIdx.x * BN;

    float acc[4][4] = {};

    for (int kt = 0; kt < K; kt += BK) {
        // Load A tile (64 rows x 16 cols), transpose into As[k][m]
        {
            const int row = tid >> 2;          // 0..63
            const int col = (tid & 3) * 4;     // 0,4,8,12
            const float4 a = *reinterpret_cast<const float4*>(
                &A[(size_t)(bm + row) * K + kt + col]);
            As[(col + 0) * LDA + row] = a.x;
            As[(col + 1) * LDA + row] = a.y;
            As[(col + 2) * LDA + row] = a.z;
            As[(col + 3) * LDA + row] = a.w;
        }
        // Load B tile (16 rows x 64 cols) directly
        {
            const int row = tid >> 4;          // 0..15
            const int col = (tid & 15) * 4;    // 0..60
            *reinterpret_cast<float4*>(&Bs[row * BN + col]) =
                *reinterpret_cast<const float4*>(
                    &B[(size_t)(kt + row) * N + bn + col]);
        }
        __syncthreads();

        #pragma unroll
        for (int kk = 0; kk < BK; ++kk) {
            const float4 af = *reinterpret_cast<const float4*>(&As[kk * LDA + ty * 4]);
            const float4 bf = *reinterpret_cast<const float4*>(&Bs[kk * BN + tx * 4]);
            const float av[4] = {af.x, af.y, af.z, af.w};
            const float bv[4] = {bf.x, bf.y, bf.z, bf.w};
            #pragma unroll
            for (int i = 0; i < 4; ++i)
                #pragma unroll
                for (int j = 0; j < 4; ++j)
                    acc[i][j] = fmaf(av[i], bv[j], acc[i][j]);
        }
        __syncthreads();
    }

    #pragma unroll
    for (int i = 0; i < 4; ++i) {
        float4 o;
        o.x = acc[i][0]; o.y = acc[i][1]; o.z = acc[i][2]; o.w = acc[i][3];
        *reinterpret_cast<float4*>(&C[(size_t)(bm + ty * 4 + i) * N + bn + tx * 4]) = o;
    }
}

// ---------------- Flash-style causal attention (fp32) ----------------
// One block per (b, h, 64-row q tile). K/V chunks of 64 staged in LDS.
// 256 threads, 4x4 register tiles. Online softmax per q row.
#define BQ 64
#define BKV 64
#define LDT 68   // padded leading dim (float4-aligned: 68*4 bytes = 272, 272%16==0)

__global__ __launch_bounds__(256) void attn_f32(const float* __restrict__ Q,
                                                const float* __restrict__ K,
                                                const float* __restrict__ V,
                                                float* __restrict__ O) {
    __shared__ float Qs[HEADD * LDT];   // [d][qrow]  transposed
    __shared__ float KPs[HEADD * LDT];  // phase 1: [d][key] transposed K; phase 2: [key][qrow] P
    __shared__ float Vs[BKV * HEADD];   // [key][d]

    const int tid = threadIdx.x;
    const int tx = tid & 15;   // 0..15
    const int ty = tid >> 4;   // 0..15
    // Heavy (high qb) blocks first to reduce causal tail imbalance
    const int qb = (gridDim.x - 1) - blockIdx.x;
    const int bh = blockIdx.y;           // b*NHEAD + h
    const int b  = bh >> 4;              // NHEAD == 16
    const int h  = bh & 15;

    const size_t base = ((size_t)b * SEQ) * DMODEL + (size_t)h * HEADD;
    const int q0 = qb * BQ;

    // Stage Q tile transposed: Qs[d][row]
    #pragma unroll
    for (int it = 0; it < 4; ++it) {
        const int row = (tid >> 4) + it * 16;   // 0..63
        const int col = (tid & 15) * 4;         // 0..60
        const float4 qv = *reinterpret_cast<const float4*>(
            &Q[base + (size_t)(q0 + row) * DMODEL + col]);
        Qs[(col + 0) * LDT + row] = qv.x;
        Qs[(col + 1) * LDT + row] = qv.y;
        Qs[(col + 2) * LDT + row] = qv.z;
        Qs[(col + 3) * LDT + row] = qv.w;
    }

    float accO[4][4] = {};
    float m_i[4], l_i[4];
    #pragma unroll
    for (int i = 0; i < 4; ++i) { m_i[i] = -INFINITY; l_i[i] = 0.0f; }

    const float scale = 0.125f;  // 1/sqrt(64)

    for (int kc = 0; kc <= qb; ++kc) {
        const int k0 = kc * BKV;
        __syncthreads();  // previous PV reads done before overwriting KPs/Vs

        // Stage K chunk transposed into KPs[d][key]; V chunk natural into Vs[key][d]
        #pragma unroll
        for (int it = 0; it < 4; ++it) {
            const int row = (tid >> 4) + it * 16;
            const int col = (tid & 15) * 4;
            const float4 kv = *reinterpret_cast<const float4*>(
                &K[base + (size_t)(k0 + row) * DMODEL + col]);
            KPs[(col + 0) * LDT + row] = kv.x;
            KPs[(col + 1) * LDT + row] = kv.y;
            KPs[(col + 2) * LDT + row] = kv.z;
            KPs[(col + 3) * LDT + row] = kv.w;
            const float4 vv = *reinterpret_cast<const float4*>(
                &V[base + (size_t)(k0 + row) * DMODEL + col]);
            *reinterpret_cast<float4*>(&Vs[row * HEADD + col]) = vv;
        }
        __syncthreads();

        // Scores: s[i][j] = q(ty*4+i) . k(tx*4+j)
        float s[4][4] = {};
        #pragma unroll 16
        for (int d = 0; d < HEADD; ++d) {
            const float4 qf = *reinterpret_cast<const float4*>(&Qs[d * LDT + ty * 4]);
            const float4 kf = *reinterpret_cast<const float4*>(&KPs[d * LDT + tx * 4]);
            const float qv[4] = {qf.x, qf.y, qf.z, qf.w};
            const float kv[4] = {kf.x, kf.y, kf.z, kf.w};
            #pragma unroll
            for (int i = 0; i < 4; ++i)
                #pragma unroll
                for (int j = 0; j < 4; ++j)
                    s[i][j] = fmaf(qv[i], kv[j], s[i][j]);
        }
        __syncthreads();  // all KPs score reads done before P overwrite

        // Causal mask + scale + online softmax (row reductions over 16 tx lanes)
        #pragma unroll
        for (int i = 0; i < 4; ++i) {
            const int qg = q0 + ty * 4 + i;
            #pragma unroll
            for (int j = 0; j < 4; ++j) {
                const int kg = k0 + tx * 4 + j;
                s[i][j] = (kg <= qg) ? s[i][j] * scale : -INFINITY;
            }
            float mc = fmaxf(fmaxf(s[i][0], s[i][1]), fmaxf(s[i][2], s[i][3]));
            #pragma unroll
            for (int off = 1; off < 16; off <<= 1)
                mc = fmaxf(mc, __shfl_xor(mc, off, 64));
            const float mnew = fmaxf(m_i[i], mc);
            const float alpha = __expf(m_i[i] - mnew);
            m_i[i] = mnew;
            float rsum = 0.0f;
            #pragma unroll
            for (int j = 0; j < 4; ++j) {
                const float p = __expf(s[i][j] - mnew);
                s[i][j] = p;
                rsum += p;
            }
            #pragma unroll
            for (int off = 1; off < 16; off <<= 1)
                rsum += __shfl_xor(rsum, off, 64);
            l_i[i] = l_i[i] * alpha + rsum;
            #pragma unroll
            for (int j = 0; j < 4; ++j) accO[i][j] *= alpha;
        }

        // Write P transposed into KPs[key][qrow]
        #pragma unroll
        for (int i = 0; i < 4; ++i)
            #pragma unroll
            for (int j = 0; j < 4; ++j)
                KPs[(tx * 4 + j) * LDT + (ty * 4 + i)] = s[i][j];
        __syncthreads();

        // PV: accO[i][j] += P[row][key] * V[key][d]
        #pragma unroll 16
        for (int kk = 0; kk < BKV; ++kk) {
            const float4 pf = *reinterpret_cast<const float4*>(&KPs[kk * LDT + ty * 4]);
            const float4 vf = *reinterpret_cast<const float4*>(&Vs[kk * HEADD + tx * 4]);
            const float pv[4] = {pf.x, pf.y, pf.z, pf.w};
            const float vv[4] = {vf.x, vf.y, vf.z, vf.w};
            #pragma unroll
            for (int i = 0; i < 4; ++i)
                #pragma unroll
                for (int j = 0; j < 4; ++j)
                    accO[i][j] = fmaf(pv[i], vv[j], accO[i][j]);
        }
    }

    // Epilogue: normalize and store attended (head-major cols => combined layout)
    #pragma unroll
    for (int i = 0; i < 4; ++i) {
        const float inv = 1.0f / l_i[i];
        float4 o;
        o.x = accO[i][0] * inv;
        o.y = accO[i][1] * inv;
        o.z = accO[i][2] * inv;
        o.w = accO[i][3] * inv;
        *reinterpret_cast<float4*>(
            &O[base + (size_t)(q0 + ty * 4 + i) * DMODEL + tx * 4]) = o;
    }
}

// ---------------- Launch ----------------
extern "C" void kernel_launch(void* const* d_in, const int* in_sizes, int n_in,
                              void* d_out, int out_size, void* d_ws, size_t ws_size,
                              hipStream_t stream) {
    const float* x  = (const float*)d_in[0];
    const float* Wq = (const float*)d_in[1];
    const float* Wk = (const float*)d_in[2];
    const float* Wv = (const float*)d_in[3];
    const float* Wo = (const float*)d_in[4];
    float* out = (float*)d_out;

    const size_t elems = (size_t)MROWS * DMODEL;  // 4096*1024
    float* Qb = (float*)d_ws;
    float* Kb = Qb + elems;
    float* Vb = Kb + elems;
    float* Ab = Vb + elems;  // attended

    dim3 blk(256);
    dim3 gg(DMODEL / BN, MROWS / BM);   // (16, 64)

    gemm_f32<<<gg, blk, 0, stream>>>(x, Wq, Qb, MROWS, DMODEL, DMODEL);
    gemm_f32<<<gg, blk, 0, stream>>>(x, Wk, Kb, MROWS, DMODEL, DMODEL);
    gemm_f32<<<gg, blk, 0, stream>>>(x, Wv, Vb, MROWS, DMODEL, DMODEL);

    dim3 ga(SEQ / BQ, BATCH * NHEAD);   // (32, 32)
    attn_f32<<<ga, blk, 0, stream>>>(Qb, Kb, Vb, Ab);

    gemm_f32<<<gg, blk, 0, stream>>>(Ab, Wo, out, MROWS, DMODEL, DMODEL);
}

// Round 2
// 409.112 us; speedup vs baseline: 2.5630x; 2.5630x over previous
//
#include <hip/hip_runtime.h>
#include <math.h>

#define BATCH 2
#define SEQ   2048
#define DMODEL 1024
#define NHEAD 16
#define HEADD 64
#define MROWS 4096

typedef __attribute__((ext_vector_type(8))) __bf16 bf16x8;
typedef __attribute__((ext_vector_type(4))) float f32x4;

__device__ __forceinline__ ushort f2bf(float f) {
    uint u = __float_as_uint(f);
    u += 0x7fffu + ((u >> 16) & 1u);   // round-to-nearest-even
    return (ushort)(u >> 16);
}
__device__ __forceinline__ float bf2f(ushort h) {
    return __uint_as_float(((uint)h) << 16);
}

// ============ Split-bf16 3-pass MFMA GEMM: C[M,1024] = A[M,1024] @ B[1024,1024]
// 128x64 tile, BK=32, 256 threads (4 waves, each 64m x 32n).
#define GBM 128
#define GBN 64
#define GBK 32
#define LDK 40   // padded k-dim leading stride (elements); 80B rows -> 2-way max conflicts

__global__ __launch_bounds__(256, 2) void gemm_split(const float* __restrict__ A,
                                                     const float* __restrict__ B,
                                                     float* __restrict__ C) {
    __shared__ ushort Ah[GBM * LDK];
    __shared__ ushort Al[GBM * LDK];
    __shared__ ushort Bh[GBN * LDK];   // transposed: [n][k]
    __shared__ ushort Bl[GBN * LDK];

    const int t = threadIdx.x;
    const int lane = t & 63;
    const int w = t >> 6;        // wave 0..3
    const int wm = w >> 1;       // 0..1
    const int wn = w & 1;        // 0..1
    const int bm = blockIdx.y * GBM;
    const int bn = blockIdx.x * GBN;

    f32x4 acc[4][2];
    #pragma unroll
    for (int mt = 0; mt < 4; ++mt)
        #pragma unroll
        for (int nt = 0; nt < 2; ++nt)
            acc[mt][nt] = (f32x4){0.f, 0.f, 0.f, 0.f};

    for (int kt = 0; kt < DMODEL; kt += GBK) {
        __syncthreads();
        // ---- stage A tile 128x32 fp32 -> hi/lo bf16, natural [m][k]
        {
            const int kc = (t & 7) * 4;
            #pragma unroll
            for (int i = 0; i < 4; ++i) {
                const int m = (t >> 3) + 32 * i;
                const float4 a = *reinterpret_cast<const float4*>(
                    &A[(size_t)(bm + m) * DMODEL + kt + kc]);
                ushort4 h, l;
                h.x = f2bf(a.x); l.x = f2bf(a.x - bf2f(h.x));
                h.y = f2bf(a.y); l.y = f2bf(a.y - bf2f(h.y));
                h.z = f2bf(a.z); l.z = f2bf(a.z - bf2f(h.z));
                h.w = f2bf(a.w); l.w = f2bf(a.w - bf2f(h.w));
                *reinterpret_cast<ushort4*>(&Ah[m * LDK + kc]) = h;
                *reinterpret_cast<ushort4*>(&Al[m * LDK + kc]) = l;
            }
        }
        // ---- stage B tile 32x64 fp32 -> hi/lo bf16, transposed [n][k]
        {
            const int n0 = (t & 15) * 4;
            #pragma unroll
            for (int i = 0; i < 2; ++i) {
                const int k = (t >> 4) + 16 * i;
                const float4 b = *reinterpret_cast<const float4*>(
                    &B[(size_t)(kt + k) * DMODEL + bn + n0]);
                const float bv[4] = {b.x, b.y, b.z, b.w};
                #pragma unroll
                for (int j = 0; j < 4; ++j) {
                    const ushort h = f2bf(bv[j]);
                    Bh[(n0 + j) * LDK + k] = h;
                    Bl[(n0 + j) * LDK + k] = f2bf(bv[j] - bf2f(h));
                }
            }
        }
        __syncthreads();

        // ---- fragments
        bf16x8 ah[4], al[4], bhf[2], blf[2];
        #pragma unroll
        for (int mt = 0; mt < 4; ++mt) {
            const int addr = (wm * 64 + mt * 16 + (lane & 15)) * LDK + 8 * (lane >> 4);
            ah[mt] = *reinterpret_cast<const bf16x8*>(&Ah[addr]);
            al[mt] = *reinterpret_cast<const bf16x8*>(&Al[addr]);
        }
        #pragma unroll
        for (int nt = 0; nt < 2; ++nt) {
            const int addr = (wn * 32 + nt * 16 + (lane & 15)) * LDK + 8 * (lane >> 4);
            bhf[nt] = *reinterpret_cast<const bf16x8*>(&Bh[addr]);
            blf[nt] = *reinterpret_cast<const bf16x8*>(&Bl[addr]);
        }
        #pragma unroll
        for (int mt = 0; mt < 4; ++mt)
            #pragma unroll
            for (int nt = 0; nt < 2; ++nt) {
                acc[mt][nt] = __builtin_amdgcn_mfma_f32_16x16x32_bf16(ah[mt], bhf[nt], acc[mt][nt], 0, 0, 0);
                acc[mt][nt] = __builtin_amdgcn_mfma_f32_16x16x32_bf16(ah[mt], blf[nt], acc[mt][nt], 0, 0, 0);
                acc[mt][nt] = __builtin_amdgcn_mfma_f32_16x16x32_bf16(al[mt], bhf[nt], acc[mt][nt], 0, 0, 0);
            }
    }

    // ---- epilogue (C layout: col=lane&15, row=(lane>>4)*4+r)
    #pragma unroll
    for (int mt = 0; mt < 4; ++mt)
        #pragma unroll
        for (int nt = 0; nt < 2; ++nt)
            #pragma unroll
            for (int r = 0; r < 4; ++r) {
                const int row = bm + wm * 64 + mt * 16 + (lane >> 4) * 4 + r;
                const int col = bn + wn * 32 + nt * 16 + (lane & 15);
                C[(size_t)row * DMODEL + col] = acc[mt][nt][r];
            }
}

// ============ MFMA flash attention (bf16), causal.
// Block: 256 thr (4 waves x 16 q-rows), BQ=64, KV chunk=64.
#define ALD 72   // padded row stride (144B, 16B-aligned)

__global__ __launch_bounds__(256, 2) void attn_mfma(const float* __restrict__ Q,
                                                    const float* __restrict__ K,
                                                    const float* __restrict__ V,
                                                    float* __restrict__ O) {
    __shared__ ushort Kl[64 * ALD];   // [key][d]
    __shared__ ushort Vt[64 * ALD];   // [d][key]  (transposed)
    __shared__ ushort Pl[64 * ALD];   // [q][key]

    const int t = threadIdx.x;
    const int lane = t & 63;
    const int w = t >> 6;
    const int qb = (gridDim.x - 1) - blockIdx.x;   // heavy blocks first
    const int bh = blockIdx.y;
    const int b = bh >> 4;
    const int h = bh & 15;
    const size_t base = ((size_t)b * SEQ) * DMODEL + (size_t)h * HEADD;
    const int q0 = qb * 64;

    // hoist Q fragments: A-operand row=lane&15, k(=d)=32*s+8*(lane>>4)+e
    bf16x8 qf[2];
    #pragma unroll
    for (int s = 0; s < 2; ++s) {
        const float* qp = &Q[base + (size_t)(q0 + w * 16 + (lane & 15)) * DMODEL
                             + 32 * s + 8 * (lane >> 4)];
        const float4 a = *reinterpret_cast<const float4*>(qp);
        const float4 c = *reinterpret_cast<const float4*>(qp + 4);
        union { ushort u[8]; bf16x8 v; } tmp;
        tmp.u[0] = f2bf(a.x); tmp.u[1] = f2bf(a.y); tmp.u[2] = f2bf(a.z); tmp.u[3] = f2bf(a.w);
        tmp.u[4] = f2bf(c.x); tmp.u[5] = f2bf(c.y); tmp.u[6] = f2bf(c.z); tmp.u[7] = f2bf(c.w);
        qf[s] = tmp.v;
    }

    f32x4 accO[4];
    #pragma unroll
    for (int dt = 0; dt < 4; ++dt) accO[dt] = (f32x4){0.f, 0.f, 0.f, 0.f};
    float m_i[4], l_i[4];
    #pragma unroll
    for (int r = 0; r < 4; ++r) { m_i[r] = -INFINITY; l_i[r] = 0.f; }

    for (int kc = 0; kc <= qb; ++kc) {
        const int k0 = kc * 64;
        __syncthreads();
        // stage K [key][d] and V^T [d][key]
        {
            const int d0 = (t & 15) * 4;
            #pragma unroll
            for (int i = 0; i < 4; ++i) {
                const int key = (t >> 4) + 16 * i;
                const float4 kv = *reinterpret_cast<const float4*>(
                    &K[base + (size_t)(k0 + key) * DMODEL + d0]);
                ushort4 hk;
                hk.x = f2bf(kv.x); hk.y = f2bf(kv.y); hk.z = f2bf(kv.z); hk.w = f2bf(kv.w);
                *reinterpret_cast<ushort4*>(&Kl[key * ALD + d0]) = hk;
                const float4 vv = *reinterpret_cast<const float4*>(
                    &V[base + (size_t)(k0 + key) * DMODEL + d0]);
                const float vr[4] = {vv.x, vv.y, vv.z, vv.w};
                #pragma unroll
                for (int j = 0; j < 4; ++j)
                    Vt[(d0 + j) * ALD + key] = f2bf(vr[j]);
            }
        }
        __syncthreads();

        // QK^T: sc[nt] layout col=key=nt*16+(lane&15), row=q=(lane>>4)*4+r
        f32x4 sc[4];
        #pragma unroll
        for (int nt = 0; nt < 4; ++nt) {
            sc[nt] = (f32x4){0.f, 0.f, 0.f, 0.f};
            #pragma unroll
            for (int s = 0; s < 2; ++s) {
                const bf16x8 kf = *reinterpret_cast<const bf16x8*>(
                    &Kl[(nt * 16 + (lane & 15)) * ALD + 32 * s + 8 * (lane >> 4)]);
                sc[nt] = __builtin_amdgcn_mfma_f32_16x16x32_bf16(qf[s], kf, sc[nt], 0, 0, 0);
            }
        }

        // scale + causal mask (only diagonal chunk needs the mask)
        const bool diag = (kc == qb);
        #pragma unroll
        for (int nt = 0; nt < 4; ++nt)
            #pragma unroll
            for (int r = 0; r < 4; ++r) {
                float sv = sc[nt][r] * 0.125f;
                if (diag) {
                    const int kg = k0 + nt * 16 + (lane & 15);
                    const int qg = q0 + w * 16 + (lane >> 4) * 4 + r;
                    if (kg > qg) sv = -INFINITY;
                }
                sc[nt][r] = sv;
            }

        // online softmax per q-row r (reduce over 16 lanes of key dim)
        #pragma unroll
        for (int r = 0; r < 4; ++r) {
            float mc = fmaxf(fmaxf(sc[0][r], sc[1][r]), fmaxf(sc[2][r], sc[3][r]));
            #pragma unroll
            for (int off = 1; off < 16; off <<= 1)
                mc = fmaxf(mc, __shfl_xor(mc, off, 64));
            const float mnew = fmaxf(m_i[r], mc);
            const float alpha = __expf(m_i[r] - mnew);
            m_i[r] = mnew;
            float rs = 0.f;
            #pragma unroll
            for (int nt = 0; nt < 4; ++nt) {
                const float p = __expf(sc[nt][r] - mnew);
                sc[nt][r] = p;
                rs += p;
            }
            #pragma unroll
            for (int off = 1; off < 16; off <<= 1)
                rs += __shfl_xor(rs, off, 64);
            l_i[r] = l_i[r] * alpha + rs;
            #pragma unroll
            for (int dt = 0; dt < 4; ++dt) accO[dt][r] *= alpha;
        }

        // P -> LDS bf16 [q][key] (wave-local band)
        #pragma unroll
        for (int nt = 0; nt < 4; ++nt)
            #pragma unroll
            for (int r = 0; r < 4; ++r)
                Pl[(w * 16 + (lane >> 4) * 4 + r) * ALD + nt * 16 + (lane & 15)] =
                    f2bf(sc[nt][r]);

        // PV: A = P (row=q=lane&15, k=key), B = V^T (col=d, k=key)
        bf16x8 pf[2];
        #pragma unroll
        for (int s = 0; s < 2; ++s)
            pf[s] = *reinterpret_cast<const bf16x8*>(
                &Pl[(w * 16 + (lane & 15)) * ALD + 32 * s + 8 * (lane >> 4)]);
        #pragma unroll
        for (int dt = 0; dt < 4; ++dt)
            #pragma unroll
            for (int s = 0; s < 2; ++s) {
                const bf16x8 vf = *reinterpret_cast<const bf16x8*>(
                    &Vt[(dt * 16 + (lane & 15)) * ALD + 32 * s + 8 * (lane >> 4)]);
                accO[dt] = __builtin_amdgcn_mfma_f32_16x16x32_bf16(pf[s], vf, accO[dt], 0, 0, 0);
            }
    }

    // epilogue: normalize, store
    #pragma unroll
    for (int r = 0; r < 4; ++r) {
        const float inv = 1.f / l_i[r];
        const int row = q0 + w * 16 + (lane >> 4) * 4 + r;
        #pragma unroll
        for (int dt = 0; dt < 4; ++dt)
            O[base + (size_t)row * DMODEL + dt * 16 + (lane & 15)] = accO[dt][r] * inv;
    }
}

// ============ launch
extern "C" void kernel_launch(void* const* d_in, const int* in_sizes, int n_in,
                              void* d_out, int out_size, void* d_ws, size_t ws_size,
                              hipStream_t stream) {
    const float* x  = (const float*)d_in[0];
    const float* Wq = (const float*)d_in[1];
    const float* Wk = (const float*)d_in[2];
    const float* Wv = (const float*)d_in[3];
    const float* Wo = (const float*)d_in[4];
    float* out = (float*)d_out;

    const size_t elems = (size_t)MROWS * DMODEL;
    float* Qb = (float*)d_ws;
    float* Kb = Qb + elems;
    float* Vb = Kb + elems;
    float* Ab = Vb + elems;

    dim3 blk(256);
    dim3 gg(DMODEL / GBN, MROWS / GBM);   // (16, 32)
    gemm_split<<<gg, blk, 0, stream>>>(x, Wq, Qb);
    gemm_split<<<gg, blk, 0, stream>>>(x, Wk, Kb);
    gemm_split<<<gg, blk, 0, stream>>>(x, Wv, Vb);

    dim3 ga(SEQ / 64, BATCH * NHEAD);     // (32, 32)
    attn_mfma<<<ga, blk, 0, stream>>>(Qb, Kb, Vb, Ab);

    gemm_split<<<gg, blk, 0, stream>>>(Ab, Wo, out);
}

// Round 3
// 283.451 us; speedup vs baseline: 3.6993x; 1.4433x over previous
//
#include <hip/hip_runtime.h>
#include <math.h>

#define BATCH 2
#define SEQ   2048
#define DMODEL 1024
#define NHEAD 16
#define HEADD 64
#define MROWS 4096

typedef __attribute__((ext_vector_type(8))) __bf16 bf16x8;
typedef __attribute__((ext_vector_type(4))) float f32x4;

__device__ __forceinline__ ushort f2bf(float f) {
    uint u = __float_as_uint(f);
    u += 0x7fffu + ((u >> 16) & 1u);
    return (ushort)(u >> 16);
}
__device__ __forceinline__ float bf2f(ushort h) {
    return __uint_as_float(((uint)h) << 16);
}

// global_load_lds: 16B per lane, dest = wave-uniform base + lane*16
#define GLD16(gsrc, ldst)                                                         \
    __builtin_amdgcn_global_load_lds(                                             \
        (const __attribute__((address_space(1))) unsigned int*)(gsrc),            \
        (__attribute__((address_space(3))) unsigned int*)(ldst), 16, 0, 0)

// ---------------- prep: split x (fp32 -> hi/lo bf16) ----------------
__global__ __launch_bounds__(256) void split_x(const float* __restrict__ in,
                                               ushort* __restrict__ oh,
                                               ushort* __restrict__ ol, int n4) {
    int i = blockIdx.x * 256 + threadIdx.x;
    const int stride = gridDim.x * 256;
    for (; i < n4; i += stride) {
        const float4 v = reinterpret_cast<const float4*>(in)[i];
        ushort4 h, l;
        h.x = f2bf(v.x); l.x = f2bf(v.x - bf2f(h.x));
        h.y = f2bf(v.y); l.y = f2bf(v.y - bf2f(h.y));
        h.z = f2bf(v.z); l.z = f2bf(v.z - bf2f(h.z));
        h.w = f2bf(v.w); l.w = f2bf(v.w - bf2f(h.w));
        reinterpret_cast<ushort4*>(oh)[i] = h;
        reinterpret_cast<ushort4*>(ol)[i] = l;
    }
}

// ---------------- prep: W [k][n] fp32 -> W^T hi/lo bf16 [n][k] ----------------
__global__ __launch_bounds__(256) void tsplit_w(const float* __restrict__ W,
                                                ushort* __restrict__ th,
                                                ushort* __restrict__ tl) {
    __shared__ float T[64][68];
    const int t = threadIdx.x;
    const int k0 = blockIdx.y * 64, n0 = blockIdx.x * 64;
    {
        const int r = t >> 2, c0 = (t & 3) * 16;
        #pragma unroll
        for (int j = 0; j < 4; ++j)
            *reinterpret_cast<float4*>(&T[r][c0 + j * 4]) =
                *reinterpret_cast<const float4*>(&W[(size_t)(k0 + r) * DMODEL + n0 + c0 + j * 4]);
    }
    __syncthreads();
    const int nl = t >> 2, kq = t & 3;
    ushort hb[16], lb[16];
    #pragma unroll
    for (int e = 0; e < 16; ++e) {
        const float v = T[kq * 16 + e][nl];
        const ushort h = f2bf(v);
        hb[e] = h; lb[e] = f2bf(v - bf2f(h));
    }
    const size_t o = (size_t)(n0 + nl) * DMODEL + k0 + kq * 16;
    *reinterpret_cast<uint4*>(&th[o]) = *reinterpret_cast<uint4*>(&hb[0]);
    *reinterpret_cast<uint4*>(&th[o + 8]) = *reinterpret_cast<uint4*>(&hb[8]);
    *reinterpret_cast<uint4*>(&tl[o]) = *reinterpret_cast<uint4*>(&lb[0]);
    *reinterpret_cast<uint4*>(&tl[o + 8]) = *reinterpret_cast<uint4*>(&lb[8]);
}

// ---------------- 3-pass split-bf16 GEMM, 64x64 tile, BK=64 ----------------
// A: [m][k] hi/lo bf16 (row stride 1024). B: W^T [n][k] hi/lo bf16.
// MODE 0: C bf16 natural [m][1024]. MODE 1: V^T bf16 [b,h,d,key]. MODE 2: C fp32.
template <int MODE>
__global__ __launch_bounds__(256, 2) void gemm3(const ushort* __restrict__ Ahg,
                                                const ushort* __restrict__ Alg,
                                                const ushort* __restrict__ Bhg,
                                                const ushort* __restrict__ Blg,
                                                void* __restrict__ Cout) {
    __shared__ ushort SH[4 * 64 * 64];   // Ah | Al | Bh | Bl, 8KB each
    ushort* const Ah = SH;
    ushort* const Al = SH + 4096;
    ushort* const Bh = SH + 8192;
    ushort* const Bl = SH + 12288;

    const int t = threadIdx.x, lane = t & 63, w = t >> 6;
    const int l = lane & 15, g = lane >> 4;
    const int wm = w >> 1, wn = w & 1;
    const int bm = blockIdx.y * 64, bn = blockIdx.x * 64;

    const ushort* gsrc = (w == 0) ? Ahg : (w == 1) ? Alg : (w == 2) ? Bhg : Blg;
    const int rowbase = (w < 2) ? bm : bn;
    ushort* const ldst = SH + w * 4096;

    f32x4 acc[2][2];
    #pragma unroll
    for (int mt = 0; mt < 2; ++mt)
        #pragma unroll
        for (int nt = 0; nt < 2; ++nt) acc[mt][nt] = (f32x4){0.f, 0.f, 0.f, 0.f};

    for (int kt = 0; kt < DMODEL; kt += 64) {
        __syncthreads();
        #pragma unroll
        for (int i = 0; i < 8; ++i) {
            const int row = 8 * i + (lane >> 3);
            const int c = lane & 7;
            GLD16(gsrc + (size_t)(rowbase + row) * DMODEL + kt + ((c ^ (row & 7)) << 3),
                  ldst + i * 512);
        }
        __syncthreads();

        bf16x8 af[2][2][2], bf[2][2][2];   // [mt/nt][s][h/l]
        #pragma unroll
        for (int mt = 0; mt < 2; ++mt)
            #pragma unroll
            for (int s = 0; s < 2; ++s) {
                const int m = wm * 32 + mt * 16 + l;
                const int off = m * 64 + (((g + 4 * s) ^ (m & 7)) << 3);
                af[mt][s][0] = *reinterpret_cast<const bf16x8*>(&Ah[off]);
                af[mt][s][1] = *reinterpret_cast<const bf16x8*>(&Al[off]);
            }
        #pragma unroll
        for (int nt = 0; nt < 2; ++nt)
            #pragma unroll
            for (int s = 0; s < 2; ++s) {
                const int n = wn * 32 + nt * 16 + l;
                const int off = n * 64 + (((g + 4 * s) ^ (n & 7)) << 3);
                bf[nt][s][0] = *reinterpret_cast<const bf16x8*>(&Bh[off]);
                bf[nt][s][1] = *reinterpret_cast<const bf16x8*>(&Bl[off]);
            }
        #pragma unroll
        for (int mt = 0; mt < 2; ++mt)
            #pragma unroll
            for (int nt = 0; nt < 2; ++nt)
                #pragma unroll
                for (int s = 0; s < 2; ++s) {
                    acc[mt][nt] = __builtin_amdgcn_mfma_f32_16x16x32_bf16(af[mt][s][0], bf[nt][s][0], acc[mt][nt], 0, 0, 0);
                    acc[mt][nt] = __builtin_amdgcn_mfma_f32_16x16x32_bf16(af[mt][s][0], bf[nt][s][1], acc[mt][nt], 0, 0, 0);
                    acc[mt][nt] = __builtin_amdgcn_mfma_f32_16x16x32_bf16(af[mt][s][1], bf[nt][s][0], acc[mt][nt], 0, 0, 0);
                }
    }

    if constexpr (MODE == 0) {
        ushort* C = (ushort*)Cout;
        #pragma unroll
        for (int mt = 0; mt < 2; ++mt)
            #pragma unroll
            for (int nt = 0; nt < 2; ++nt)
                #pragma unroll
                for (int r = 0; r < 4; ++r) {
                    const int row = bm + wm * 32 + mt * 16 + g * 4 + r;
                    const int col = bn + wn * 32 + nt * 16 + l;
                    C[(size_t)row * DMODEL + col] = f2bf(acc[mt][nt][r]);
                }
    } else if constexpr (MODE == 2) {
        float* C = (float*)Cout;
        #pragma unroll
        for (int mt = 0; mt < 2; ++mt)
            #pragma unroll
            for (int nt = 0; nt < 2; ++nt)
                #pragma unroll
                for (int r = 0; r < 4; ++r) {
                    const int row = bm + wm * 32 + mt * 16 + g * 4 + r;
                    const int col = bn + wn * 32 + nt * 16 + l;
                    C[(size_t)row * DMODEL + col] = acc[mt][nt][r];
                }
    } else {
        // V^T epilogue: LDS transpose then coalesced rows of [d][key]
        __syncthreads();
        ushort* VtL = SH;   // [64 d][72 key]
        #pragma unroll
        for (int mt = 0; mt < 2; ++mt)
            #pragma unroll
            for (int nt = 0; nt < 2; ++nt)
                #pragma unroll
                for (int r = 0; r < 4; ++r) {
                    const int dl = wn * 32 + nt * 16 + l;
                    const int kl = wm * 32 + mt * 16 + g * 4 + r;
                    VtL[dl * 72 + kl] = f2bf(acc[mt][nt][r]);
                }
        __syncthreads();
        const int dl = t >> 2, kq = t & 3;
        const int bb = bm >> 11, head = bn >> 6, key0 = bm & 2047;
        ushort* C = (ushort*)Cout;
        const size_t o = ((size_t)((bb * 16 + head) * 64 + dl)) * SEQ + key0 + kq * 16;
        *reinterpret_cast<uint4*>(&C[o]) = *reinterpret_cast<uint4*>(&VtL[dl * 72 + kq * 16]);
        *reinterpret_cast<uint4*>(&C[o + 8]) = *reinterpret_cast<uint4*>(&VtL[dl * 72 + kq * 16 + 8]);
    }
}

// ---------------- flash attention: bf16 operands, BQ=32, 2 waves ----------------
__global__ __launch_bounds__(128) void attn(const ushort* __restrict__ Q,
                                            const ushort* __restrict__ K,
                                            const ushort* __restrict__ Vt,
                                            ushort* __restrict__ ATh,
                                            ushort* __restrict__ ATl) {
    __shared__ ushort Kl[64 * 64];
    __shared__ ushort Vl[64 * 64];
    __shared__ ushort Pl[32 * 72];

    const int t = threadIdx.x, lane = t & 63, w = t >> 6;
    const int l = lane & 15, g = lane >> 4;
    const int qb = 63 - blockIdx.x;     // heavy blocks first
    const int bh = blockIdx.y, b = bh >> 4, h = bh & 15;
    const int q0 = qb * 32;

    // Q A-fragments (row = lane&15, k = 32s + 8g + e), direct bf16 loads
    bf16x8 qf[2];
    {
        const size_t qoff = (size_t)(b * SEQ + q0 + w * 16 + l) * DMODEL + h * 64;
        qf[0] = *reinterpret_cast<const bf16x8*>(&Q[qoff + g * 8]);
        qf[1] = *reinterpret_cast<const bf16x8*>(&Q[qoff + 32 + g * 8]);
    }

    f32x4 accO[4];
    #pragma unroll
    for (int dt = 0; dt < 4; ++dt) accO[dt] = (f32x4){0.f, 0.f, 0.f, 0.f};
    float m_i[4], l_i[4];
    #pragma unroll
    for (int r = 0; r < 4; ++r) { m_i[r] = -INFINITY; l_i[r] = 0.f; }

    const int nch = (qb >> 1) + 1;
    const size_t kbase = (size_t)b * SEQ * DMODEL + h * 64;
    const size_t vbase = (size_t)bh * 64 * SEQ;

    for (int kc = 0; kc < nch; ++kc) {
        const int k0 = kc * 64;
        __syncthreads();
        #pragma unroll
        for (int i = 0; i < 4; ++i) {
            const int j = 4 * w + i;
            const int row = 8 * j + (lane >> 3);
            const int c = lane & 7;
            const int sw = (c ^ (row & 7)) << 3;
            GLD16(K + kbase + (size_t)(k0 + row) * DMODEL + sw, Kl + j * 512);
            GLD16(Vt + vbase + (size_t)row * SEQ + k0 + sw, Vl + j * 512);
        }
        __syncthreads();

        // QK^T
        f32x4 sc[4];
        #pragma unroll
        for (int nt = 0; nt < 4; ++nt) {
            sc[nt] = (f32x4){0.f, 0.f, 0.f, 0.f};
            const int key = nt * 16 + l;
            #pragma unroll
            for (int s = 0; s < 2; ++s) {
                const bf16x8 kf = *reinterpret_cast<const bf16x8*>(
                    &Kl[key * 64 + (((g + 4 * s) ^ (key & 7)) << 3)]);
                sc[nt] = __builtin_amdgcn_mfma_f32_16x16x32_bf16(qf[s], kf, sc[nt], 0, 0, 0);
            }
        }

        // scale + causal mask (diag chunk only) + online softmax
        const bool diag = (kc == nch - 1);
        #pragma unroll
        for (int nt = 0; nt < 4; ++nt)
            #pragma unroll
            for (int r = 0; r < 4; ++r) {
                float sv = sc[nt][r] * 0.125f;
                if (diag) {
                    const int kg = k0 + nt * 16 + l;
                    const int qg = q0 + w * 16 + g * 4 + r;
                    if (kg > qg) sv = -INFINITY;
                }
                sc[nt][r] = sv;
            }
        #pragma unroll
        for (int r = 0; r < 4; ++r) {
            float mc = fmaxf(fmaxf(sc[0][r], sc[1][r]), fmaxf(sc[2][r], sc[3][r]));
            #pragma unroll
            for (int off = 1; off < 16; off <<= 1)
                mc = fmaxf(mc, __shfl_xor(mc, off, 64));
            const float mnew = fmaxf(m_i[r], mc);
            const float alpha = __expf(m_i[r] - mnew);
            m_i[r] = mnew;
            float rs = 0.f;
            #pragma unroll
            for (int nt = 0; nt < 4; ++nt) {
                const float p = __expf(sc[nt][r] - mnew);
                sc[nt][r] = p;
                rs += p;
            }
            #pragma unroll
            for (int off = 1; off < 16; off <<= 1)
                rs += __shfl_xor(rs, off, 64);
            l_i[r] = l_i[r] * alpha + rs;
            #pragma unroll
            for (int dt = 0; dt < 4; ++dt) accO[dt][r] *= alpha;
        }

        // P -> LDS (wave-private rows; no barrier needed)
        #pragma unroll
        for (int nt = 0; nt < 4; ++nt)
            #pragma unroll
            for (int r = 0; r < 4; ++r)
                Pl[(w * 16 + g * 4 + r) * 72 + nt * 16 + l] = f2bf(sc[nt][r]);

        // PV
        bf16x8 pf[2];
        #pragma unroll
        for (int s = 0; s < 2; ++s)
            pf[s] = *reinterpret_cast<const bf16x8*>(&Pl[(w * 16 + l) * 72 + s * 32 + g * 8]);
        #pragma unroll
        for (int dt = 0; dt < 4; ++dt) {
            const int d = dt * 16 + l;
            #pragma unroll
            for (int s = 0; s < 2; ++s) {
                const bf16x8 vf = *reinterpret_cast<const bf16x8*>(
                    &Vl[d * 64 + (((g + 4 * s) ^ (d & 7)) << 3)]);
                accO[dt] = __builtin_amdgcn_mfma_f32_16x16x32_bf16(pf[s], vf, accO[dt], 0, 0, 0);
            }
        }
    }

    // epilogue: normalize, emit attended hi/lo bf16
    #pragma unroll
    for (int r = 0; r < 4; ++r) {
        const float inv = 1.f / l_i[r];
        const size_t row = (size_t)(b * SEQ + q0 + w * 16 + g * 4 + r) * DMODEL + h * 64;
        #pragma unroll
        for (int dt = 0; dt < 4; ++dt) {
            const float val = accO[dt][r] * inv;
            const ushort hh = f2bf(val);
            ATh[row + dt * 16 + l] = hh;
            ATl[row + dt * 16 + l] = f2bf(val - bf2f(hh));
        }
    }
}

// ---------------- launch ----------------
extern "C" void kernel_launch(void* const* d_in, const int* in_sizes, int n_in,
                              void* d_out, int out_size, void* d_ws, size_t ws_size,
                              hipStream_t stream) {
    const float* x  = (const float*)d_in[0];
    const float* Wq = (const float*)d_in[1];
    const float* Wk = (const float*)d_in[2];
    const float* Wv = (const float*)d_in[3];
    const float* Wo = (const float*)d_in[4];
    float* out = (float*)d_out;

    char* ws = (char*)d_ws;
    const size_t MB = 1024 * 1024;
    ushort* xh = (ushort*)(ws);                 // 8 MB
    ushort* xl = (ushort*)(ws + 8 * MB);        // 8 MB
    ushort* ath = xh;                           // alias (x splits dead after V gemm)
    ushort* atl = xl;
    ushort* wth[4], *wtl[4];
    for (int i = 0; i < 4; ++i) {
        wth[i] = (ushort*)(ws + 16 * MB + (size_t)i * 2 * MB);
        wtl[i] = (ushort*)(ws + 24 * MB + (size_t)i * 2 * MB);
    }
    ushort* Qb  = (ushort*)(ws + 32 * MB);      // 8 MB
    ushort* Kb  = (ushort*)(ws + 40 * MB);      // 8 MB
    ushort* Vtb = (ushort*)(ws + 48 * MB);      // 8 MB

    const float* Ws[4] = {Wq, Wk, Wv, Wo};

    split_x<<<2048, 256, 0, stream>>>(x, xh, xl, MROWS * DMODEL / 4);
    for (int i = 0; i < 4; ++i)
        tsplit_w<<<dim3(16, 16), 256, 0, stream>>>(Ws[i], wth[i], wtl[i]);

    dim3 gg(DMODEL / 64, MROWS / 64);   // (16, 64)
    gemm3<0><<<gg, 256, 0, stream>>>(xh, xl, wth[0], wtl[0], Qb);
    gemm3<0><<<gg, 256, 0, stream>>>(xh, xl, wth[1], wtl[1], Kb);
    gemm3<1><<<gg, 256, 0, stream>>>(xh, xl, wth[2], wtl[2], Vtb);

    dim3 ga(SEQ / 32, BATCH * NHEAD);   // (64, 32)
    attn<<<ga, 128, 0, stream>>>(Qb, Kb, Vtb, ath, atl);

    gemm3<2><<<gg, 256, 0, stream>>>(ath, atl, wth[3], wtl[3], out);
}

// Round 5
// 203.455 us; speedup vs baseline: 5.1538x; 1.3932x over previous
//
#include <hip/hip_runtime.h>
#include <math.h>

#define BATCH 2
#define SEQ   2048
#define DMODEL 1024
#define NHEAD 16
#define HEADD 64
#define MROWS 4096

typedef __attribute__((ext_vector_type(8))) __bf16 bf16x8;
typedef __attribute__((ext_vector_type(4))) float f32x4;

__device__ __forceinline__ ushort f2bf(float f) {
    uint u = __float_as_uint(f);
    u += 0x7fffu + ((u >> 16) & 1u);
    return (ushort)(u >> 16);
}
__device__ __forceinline__ float bf2f(ushort h) {
    return __uint_as_float(((uint)h) << 16);
}
__device__ __forceinline__ ushort4 pack4bf(float a, float b, float c, float d) {
    union { __bf16 h[4]; ushort4 u; } p;
    p.h[0] = (__bf16)a; p.h[1] = (__bf16)b; p.h[2] = (__bf16)c; p.h[3] = (__bf16)d;
    return p.u;
}

#define GLD16(gsrc, ldst)                                                         \
    __builtin_amdgcn_global_load_lds(                                             \
        (const __attribute__((address_space(1))) unsigned int*)(gsrc),            \
        (__attribute__((address_space(3))) unsigned int*)(ldst), 16, 0, 0)

// Q pre-scale: (1/sqrt(64)) * log2(e)  -> softmax in exp2 domain
#define QSCALE 0.1803368801111204f

// ---------------- prep: x fp32 -> bf16 (hi only) ----------------
__global__ __launch_bounds__(256) void split_x(const float* __restrict__ in,
                                               ushort* __restrict__ oh, int n4) {
    int i = blockIdx.x * 256 + threadIdx.x;
    const int stride = gridDim.x * 256;
    for (; i < n4; i += stride) {
        const float4 v = reinterpret_cast<const float4*>(in)[i];
        ushort4 h;
        h.x = f2bf(v.x); h.y = f2bf(v.y); h.z = f2bf(v.z); h.w = f2bf(v.w);
        reinterpret_cast<ushort4*>(oh)[i] = h;
    }
}

// ---------------- prep: W^T; z<3 -> combined QKV hi; z==3 -> Wo hi/lo ----------------
__global__ __launch_bounds__(256) void tsplit_w(const float* __restrict__ Wq,
                                                const float* __restrict__ Wk,
                                                const float* __restrict__ Wv,
                                                const float* __restrict__ Wo,
                                                ushort* __restrict__ wtc,
                                                ushort* __restrict__ woh,
                                                ushort* __restrict__ wol) {
    const int z = blockIdx.z;
    const float* W = (z == 0) ? Wq : (z == 1) ? Wk : (z == 2) ? Wv : Wo;
    __shared__ float T[64][68];
    const int t = threadIdx.x;
    const int k0 = blockIdx.y * 64, n0 = blockIdx.x * 64;
    {
        const int r = t >> 2, c0 = (t & 3) * 16;
        #pragma unroll
        for (int j = 0; j < 4; ++j)
            *reinterpret_cast<float4*>(&T[r][c0 + j * 4]) =
                *reinterpret_cast<const float4*>(&W[(size_t)(k0 + r) * DMODEL + n0 + c0 + j * 4]);
    }
    __syncthreads();
    const int nl = t >> 2, kq = t & 3;
    if (z < 3) {
        ushort hb[16];
        #pragma unroll
        for (int e = 0; e < 16; ++e) hb[e] = f2bf(T[kq * 16 + e][nl]);
        const size_t o = (size_t)(z * 1024 + n0 + nl) * DMODEL + k0 + kq * 16;
        *reinterpret_cast<uint4*>(&wtc[o]) = *reinterpret_cast<uint4*>(&hb[0]);
        *reinterpret_cast<uint4*>(&wtc[o + 8]) = *reinterpret_cast<uint4*>(&hb[8]);
    } else {
        ushort hb[16], lb[16];
        #pragma unroll
        for (int e = 0; e < 16; ++e) {
            const float v = T[kq * 16 + e][nl];
            const ushort h = f2bf(v);
            hb[e] = h; lb[e] = f2bf(v - bf2f(h));
        }
        const size_t o = (size_t)(n0 + nl) * DMODEL + k0 + kq * 16;
        *reinterpret_cast<uint4*>(&woh[o]) = *reinterpret_cast<uint4*>(&hb[0]);
        *reinterpret_cast<uint4*>(&woh[o + 8]) = *reinterpret_cast<uint4*>(&hb[8]);
        *reinterpret_cast<uint4*>(&wol[o]) = *reinterpret_cast<uint4*>(&lb[0]);
        *reinterpret_cast<uint4*>(&wol[o + 8]) = *reinterpret_cast<uint4*>(&lb[8]);
    }
}

// ---------------- fused QKV GEMM: single-pass bf16, 128x128 tile, BK=64 ----------------
// mode by bn>>10: 0 -> Q (scaled bf16), 1 -> K (bf16), 2 -> V^T [b,h,d,key]
__global__ __launch_bounds__(512) void gemm_qkv(const ushort* __restrict__ xh,
                                                const ushort* __restrict__ wtc,
                                                ushort* __restrict__ Qb,
                                                ushort* __restrict__ Kb,
                                                ushort* __restrict__ Vtb) {
    __shared__ ushort SH[17408];   // staging 32KB (Ah|Bh) ; V^T transpose 128x136
    ushort* const Ah = SH;
    ushort* const Bh = SH + 8192;

    const int t = threadIdx.x, lane = t & 63, w = t >> 6;
    const int l = lane & 15, g = lane >> 4;
    const int wm = w >> 2, wn = w & 3;            // 2 x 4 wave grid, wave = 64m x 32n
    const int bm = blockIdx.y * 128, bn = blockIdx.x * 128;

    f32x4 acc[4][2];
    #pragma unroll
    for (int mt = 0; mt < 4; ++mt)
        #pragma unroll
        for (int nt = 0; nt < 2; ++nt) acc[mt][nt] = (f32x4){0.f, 0.f, 0.f, 0.f};

    for (int kt = 0; kt < DMODEL; kt += 64) {
        __syncthreads();
        #pragma unroll
        for (int i = 0; i < 4; ++i) {
            const int sid = w * 4 + i;            // 0..31
            const int c = sid & 15;
            const ushort* src = (sid < 16) ? xh : wtc;
            const int rb = (sid < 16) ? bm : bn;
            ushort* dst = ((sid < 16) ? Ah : Bh) + c * 512;
            const int row = c * 8 + (lane >> 3);
            const int sw = ((lane & 7) ^ (row & 7)) << 3;
            GLD16(src + (size_t)(rb + row) * DMODEL + kt + sw, dst);
        }
        __syncthreads();

        bf16x8 af[4][2], bf[2][2];
        #pragma unroll
        for (int mt = 0; mt < 4; ++mt)
            #pragma unroll
            for (int s = 0; s < 2; ++s) {
                const int m = wm * 64 + mt * 16 + l;
                af[mt][s] = *reinterpret_cast<const bf16x8*>(&Ah[m * 64 + (((g + 4 * s) ^ (m & 7)) << 3)]);
            }
        #pragma unroll
        for (int nt = 0; nt < 2; ++nt)
            #pragma unroll
            for (int s = 0; s < 2; ++s) {
                const int n = wn * 32 + nt * 16 + l;
                bf[nt][s] = *reinterpret_cast<const bf16x8*>(&Bh[n * 64 + (((g + 4 * s) ^ (n & 7)) << 3)]);
            }
        #pragma unroll
        for (int mt = 0; mt < 4; ++mt)
            #pragma unroll
            for (int nt = 0; nt < 2; ++nt)
                #pragma unroll
                for (int s = 0; s < 2; ++s)
                    acc[mt][nt] = __builtin_amdgcn_mfma_f32_16x16x32_bf16(af[mt][s], bf[nt][s], acc[mt][nt], 0, 0, 0);
    }

    const int mode = bn >> 10;
    if (mode == 0) {
        #pragma unroll
        for (int mt = 0; mt < 4; ++mt)
            #pragma unroll
            for (int nt = 0; nt < 2; ++nt)
                #pragma unroll
                for (int r = 0; r < 4; ++r) {
                    const int row = bm + wm * 64 + mt * 16 + g * 4 + r;
                    const int col = bn + wn * 32 + nt * 16 + l;
                    Qb[(size_t)row * DMODEL + col] = f2bf(acc[mt][nt][r] * QSCALE);
                }
    } else if (mode == 1) {
        #pragma unroll
        for (int mt = 0; mt < 4; ++mt)
            #pragma unroll
            for (int nt = 0; nt < 2; ++nt)
                #pragma unroll
                for (int r = 0; r < 4; ++r) {
                    const int row = bm + wm * 64 + mt * 16 + g * 4 + r;
                    const int col = (bn - 1024) + wn * 32 + nt * 16 + l;
                    Kb[(size_t)row * DMODEL + col] = f2bf(acc[mt][nt][r]);
                }
    } else {
        __syncthreads();
        ushort* VtL = SH;   // [128 d][136 key]
        #pragma unroll
        for (int mt = 0; mt < 4; ++mt)
            #pragma unroll
            for (int nt = 0; nt < 2; ++nt)
                #pragma unroll
                for (int r = 0; r < 4; ++r) {
                    const int dl = wn * 32 + nt * 16 + l;
                    const int kl = wm * 64 + mt * 16 + g * 4 + r;
                    VtL[dl * 136 + kl] = f2bf(acc[mt][nt][r]);
                }
        __syncthreads();
        const int dl = t >> 2, kq = t & 3;
        const int b = bm >> 11;
        const int row = b * 1024 + (bn - 2048) + dl;     // (b*16+h)*64 + d
        const int key0 = bm & 2047;
        const size_t o = (size_t)row * SEQ + key0 + kq * 32;
        #pragma unroll
        for (int j = 0; j < 4; ++j)   // FIX: 4 x uint4 = 32 keys/thread, full 128-key coverage
            *reinterpret_cast<uint4*>(&Vtb[o + j * 8]) =
                *reinterpret_cast<uint4*>(&VtL[dl * 136 + kq * 32 + j * 8]);
    }
}

// ---------------- attention: no barriers, K/V from L2, swapped QK^T ----------------
// block = 128 thr (2 waves), wave = 32 q-rows (2 sets of 16), BQ=64/block.
#define LDP 72

__global__ __launch_bounds__(128) void attn(const ushort* __restrict__ Q,
                                            const ushort* __restrict__ K,
                                            const ushort* __restrict__ Vt,
                                            ushort* __restrict__ ATh,
                                            ushort* __restrict__ ATl) {
    __shared__ ushort Pl[64 * LDP];   // wave-private rows

    const int t = threadIdx.x, lane = t & 63, w = t >> 6;
    const int l = lane & 15, g = lane >> 4;
    const int qb = 31 - blockIdx.x;               // heavy blocks first
    const int bh = blockIdx.y, b = bh >> 4, h = bh & 15;
    const int q0 = qb * 64 + w * 32;              // wave's first q-row
    const size_t kbase = (size_t)b * SEQ * DMODEL + h * 64;
    const size_t vbase = (size_t)bh * 64 * SEQ;

    // Q B-operand frags (col=q=lane&15, k=d=32s+8g+e), two 16-row sets
    bf16x8 qf[2][2];
    #pragma unroll
    for (int qs = 0; qs < 2; ++qs) {
        const size_t qoff = (size_t)(b * SEQ + q0 + qs * 16 + l) * DMODEL + h * 64;
        qf[qs][0] = *reinterpret_cast<const bf16x8*>(&Q[qoff + 8 * g]);
        qf[qs][1] = *reinterpret_cast<const bf16x8*>(&Q[qoff + 32 + 8 * g]);
    }

    f32x4 accO[2][4];
    #pragma unroll
    for (int qs = 0; qs < 2; ++qs)
        #pragma unroll
        for (int dt = 0; dt < 4; ++dt) accO[qs][dt] = (f32x4){0.f, 0.f, 0.f, 0.f};
    float m_i[2] = {-INFINITY, -INFINITY}, l_i[2] = {0.f, 0.f};

    const int nch = qb + 1;
    for (int kc = 0; kc < nch; ++kc) {
        const int k0 = kc * 64;

        // K A-frags + V^T B-frags straight from global (L2)
        bf16x8 kf[4][2], vf[4][2];
        #pragma unroll
        for (int nt = 0; nt < 4; ++nt) {
            const size_t ko = kbase + (size_t)(k0 + nt * 16 + l) * DMODEL + 8 * g;
            kf[nt][0] = *reinterpret_cast<const bf16x8*>(&K[ko]);
            kf[nt][1] = *reinterpret_cast<const bf16x8*>(&K[ko + 32]);
        }
        #pragma unroll
        for (int dt = 0; dt < 4; ++dt) {
            const size_t vo = vbase + (size_t)(dt * 16 + l) * SEQ + k0 + 8 * g;
            vf[dt][0] = *reinterpret_cast<const bf16x8*>(&Vt[vo]);
            vf[dt][1] = *reinterpret_cast<const bf16x8*>(&Vt[vo + 32]);
        }

        // swapped QK^T: sc[qs][nt] holds score[key = k0+16nt+4g+r][q = q0+16qs+l]
        f32x4 sc[2][4];
        #pragma unroll
        for (int qs = 0; qs < 2; ++qs)
            #pragma unroll
            for (int nt = 0; nt < 4; ++nt) {
                f32x4 z = (f32x4){0.f, 0.f, 0.f, 0.f};
                z = __builtin_amdgcn_mfma_f32_16x16x32_bf16(kf[nt][0], qf[qs][0], z, 0, 0, 0);
                z = __builtin_amdgcn_mfma_f32_16x16x32_bf16(kf[nt][1], qf[qs][1], z, 0, 0, 0);
                sc[qs][nt] = z;
            }

        // causal mask (diag chunk only)
        if (kc == nch - 1) {
            #pragma unroll
            for (int qs = 0; qs < 2; ++qs) {
                const int qg = q0 + qs * 16 + l;
                #pragma unroll
                for (int nt = 0; nt < 4; ++nt)
                    #pragma unroll
                    for (int r = 0; r < 4; ++r)
                        if (k0 + nt * 16 + g * 4 + r > qg) sc[qs][nt][r] = -INFINITY;
            }
        }

        // online softmax (log2 domain), per set
        #pragma unroll
        for (int qs = 0; qs < 2; ++qs) {
            float mc = sc[qs][0][0];
            #pragma unroll
            for (int nt = 0; nt < 4; ++nt)
                #pragma unroll
                for (int r = 0; r < 4; ++r) mc = fmaxf(mc, sc[qs][nt][r]);
            mc = fmaxf(mc, __shfl_xor(mc, 16, 64));
            mc = fmaxf(mc, __shfl_xor(mc, 32, 64));

            if (__any(mc > m_i[qs] + 8.f)) {          // defer-max
                const float mn = fmaxf(m_i[qs], mc);
                const float al = exp2f(m_i[qs] - mn);
                m_i[qs] = mn;
                l_i[qs] *= al;
                #pragma unroll
                for (int r = 0; r < 4; ++r) {
                    const float ar = __shfl(al, 4 * (lane >> 4) + r, 64);
                    #pragma unroll
                    for (int dt = 0; dt < 4; ++dt) accO[qs][dt][r] *= ar;
                }
            }

            float rs = 0.f;
            #pragma unroll
            for (int nt = 0; nt < 4; ++nt)
                #pragma unroll
                for (int r = 0; r < 4; ++r) {
                    const float p = exp2f(sc[qs][nt][r] - m_i[qs]);
                    sc[qs][nt][r] = p;
                    rs += p;
                }
            rs += __shfl_xor(rs, 16, 64);
            rs += __shfl_xor(rs, 32, 64);
            l_i[qs] += rs;

            // P -> LDS [qrow][key], 8B packed writes (wave-private, no barrier)
            const int prow = w * 32 + qs * 16 + l;
            #pragma unroll
            for (int nt = 0; nt < 4; ++nt)
                *reinterpret_cast<ushort4*>(&Pl[prow * LDP + nt * 16 + 4 * g]) =
                    pack4bf(sc[qs][nt][0], sc[qs][nt][1], sc[qs][nt][2], sc[qs][nt][3]);
        }

        // PV: A = P (row=q, k=key), B = V^T (col=d, k=key)
        #pragma unroll
        for (int qs = 0; qs < 2; ++qs) {
            bf16x8 pf[2];
            const int prow = w * 32 + qs * 16 + l;
            pf[0] = *reinterpret_cast<const bf16x8*>(&Pl[prow * LDP + 8 * g]);
            pf[1] = *reinterpret_cast<const bf16x8*>(&Pl[prow * LDP + 32 + 8 * g]);
            #pragma unroll
            for (int dt = 0; dt < 4; ++dt) {
                accO[qs][dt] = __builtin_amdgcn_mfma_f32_16x16x32_bf16(pf[0], vf[dt][0], accO[qs][dt], 0, 0, 0);
                accO[qs][dt] = __builtin_amdgcn_mfma_f32_16x16x32_bf16(pf[1], vf[dt][1], accO[qs][dt], 0, 0, 0);
            }
        }
    }

    // epilogue: normalize, emit attended hi/lo bf16
    #pragma unroll
    for (int qs = 0; qs < 2; ++qs) {
        #pragma unroll
        for (int r = 0; r < 4; ++r) {
            const float lr = __shfl(l_i[qs], 4 * (lane >> 4) + r, 64);
            const float inv = 1.f / lr;
            const size_t row = (size_t)(b * SEQ + q0 + qs * 16 + g * 4 + r) * DMODEL + h * 64;
            #pragma unroll
            for (int dt = 0; dt < 4; ++dt) {
                const float val = accO[qs][dt][r] * inv;
                const ushort hh = f2bf(val);
                ATh[row + dt * 16 + l] = hh;
                ATl[row + dt * 16 + l] = f2bf(val - bf2f(hh));
            }
        }
    }
}

// ---------------- out GEMM: 3-pass hi/lo, 128x64 tile, BK=64, fp32 out ----------------
__global__ __launch_bounds__(512) void gemm_o(const ushort* __restrict__ Ahg,
                                              const ushort* __restrict__ Alg,
                                              const ushort* __restrict__ Bhg,
                                              const ushort* __restrict__ Blg,
                                              float* __restrict__ C) {
    __shared__ ushort SH[24576];   // Ah 16KB | Al 16KB | Bh 8KB | Bl 8KB
    ushort* const Ah = SH;
    ushort* const Al = SH + 8192;
    ushort* const Bh = SH + 16384;
    ushort* const Bl = SH + 20480;

    const int t = threadIdx.x, lane = t & 63, w = t >> 6;
    const int l = lane & 15, g = lane >> 4;
    const int wm = w >> 1, wn = w & 1;            // 4 x 2 wave grid, wave = 32m x 32n
    const int bm = blockIdx.y * 128, bn = blockIdx.x * 64;

    f32x4 acc[2][2];
    #pragma unroll
    for (int mt = 0; mt < 2; ++mt)
        #pragma unroll
        for (int nt = 0; nt < 2; ++nt) acc[mt][nt] = (f32x4){0.f, 0.f, 0.f, 0.f};

    for (int kt = 0; kt < DMODEL; kt += 64) {
        __syncthreads();
        #pragma unroll
        for (int i = 0; i < 6; ++i) {
            const int sid = w * 6 + i;            // 0..47
            const ushort* src; ushort* dst; int rb, c;
            if (sid < 16)      { src = Ahg; dst = Ah; rb = bm; c = sid; }
            else if (sid < 32) { src = Alg; dst = Al; rb = bm; c = sid - 16; }
            else if (sid < 40) { src = Bhg; dst = Bh; rb = bn; c = sid - 32; }
            else               { src = Blg; dst = Bl; rb = bn; c = sid - 40; }
            const int row = c * 8 + (lane >> 3);
            const int sw = ((lane & 7) ^ (row & 7)) << 3;
            GLD16(src + (size_t)(rb + row) * DMODEL + kt + sw, dst + c * 512);
        }
        __syncthreads();

        bf16x8 ah[2][2], al[2][2], bhf[2][2], blf[2][2];
        #pragma unroll
        for (int mt = 0; mt < 2; ++mt)
            #pragma unroll
            for (int s = 0; s < 2; ++s) {
                const int m = wm * 32 + mt * 16 + l;
                const int off = m * 64 + (((g + 4 * s) ^ (m & 7)) << 3);
                ah[mt][s] = *reinterpret_cast<const bf16x8*>(&Ah[off]);
                al[mt][s] = *reinterpret_cast<const bf16x8*>(&Al[off]);
            }
        #pragma unroll
        for (int nt = 0; nt < 2; ++nt)
            #pragma unroll
            for (int s = 0; s < 2; ++s) {
                const int n = wn * 32 + nt * 16 + l;
                const int off = n * 64 + (((g + 4 * s) ^ (n & 7)) << 3);
                bhf[nt][s] = *reinterpret_cast<const bf16x8*>(&Bh[off]);
                blf[nt][s] = *reinterpret_cast<const bf16x8*>(&Bl[off]);
            }
        #pragma unroll
        for (int mt = 0; mt < 2; ++mt)
            #pragma unroll
            for (int nt = 0; nt < 2; ++nt)
                #pragma unroll
                for (int s = 0; s < 2; ++s) {
                    acc[mt][nt] = __builtin_amdgcn_mfma_f32_16x16x32_bf16(ah[mt][s], bhf[nt][s], acc[mt][nt], 0, 0, 0);
                    acc[mt][nt] = __builtin_amdgcn_mfma_f32_16x16x32_bf16(ah[mt][s], blf[nt][s], acc[mt][nt], 0, 0, 0);
                    acc[mt][nt] = __builtin_amdgcn_mfma_f32_16x16x32_bf16(al[mt][s], bhf[nt][s], acc[mt][nt], 0, 0, 0);
                }
    }

    #pragma unroll
    for (int mt = 0; mt < 2; ++mt)
        #pragma unroll
        for (int nt = 0; nt < 2; ++nt)
            #pragma unroll
            for (int r = 0; r < 4; ++r) {
                const int row = bm + wm * 32 + mt * 16 + g * 4 + r;
                const int col = bn + wn * 32 + nt * 16 + l;
                C[(size_t)row * DMODEL + col] = acc[mt][nt][r];
            }
}

// ---------------- launch ----------------
extern "C" void kernel_launch(void* const* d_in, const int* in_sizes, int n_in,
                              void* d_out, int out_size, void* d_ws, size_t ws_size,
                              hipStream_t stream) {
    const float* x  = (const float*)d_in[0];
    const float* Wq = (const float*)d_in[1];
    const float* Wk = (const float*)d_in[2];
    const float* Wv = (const float*)d_in[3];
    const float* Wo = (const float*)d_in[4];
    float* out = (float*)d_out;

    char* ws = (char*)d_ws;
    const size_t MB = 1024 * 1024;
    ushort* xh  = (ushort*)(ws);              // 8 MB  (aliased as ATh after QKV gemm)
    ushort* ath = xh;
    ushort* atl = (ushort*)(ws + 8 * MB);     // 8 MB
    ushort* wtc = (ushort*)(ws + 16 * MB);    // 6 MB  [3072][1024]
    ushort* woh = (ushort*)(ws + 22 * MB);    // 2 MB
    ushort* wol = (ushort*)(ws + 24 * MB);    // 2 MB
    ushort* Qb  = (ushort*)(ws + 26 * MB);    // 8 MB
    ushort* Kb  = (ushort*)(ws + 34 * MB);    // 8 MB
    ushort* Vtb = (ushort*)(ws + 42 * MB);    // 8 MB

    split_x<<<1024, 256, 0, stream>>>(x, xh, MROWS * DMODEL / 4);
    tsplit_w<<<dim3(16, 16, 4), 256, 0, stream>>>(Wq, Wk, Wv, Wo, wtc, woh, wol);

    gemm_qkv<<<dim3(24, 32), 512, 0, stream>>>(xh, wtc, Qb, Kb, Vtb);

    attn<<<dim3(32, 32), 128, 0, stream>>>(Qb, Kb, Vtb, ath, atl);

    gemm_o<<<dim3(16, 32), 512, 0, stream>>>(ath, atl, woh, wol, out);
}

// Round 6
// 200.832 us; speedup vs baseline: 5.2211x; 1.0131x over previous
//
#include <hip/hip_runtime.h>
#include <math.h>

#define BATCH 2
#define SEQ   2048
#define DMODEL 1024
#define NHEAD 16
#define HEADD 64
#define MROWS 4096

typedef __attribute__((ext_vector_type(8))) __bf16 bf16x8;
typedef __attribute__((ext_vector_type(4))) float f32x4;

__device__ __forceinline__ ushort f2bf(float f) {
    uint u = __float_as_uint(f);
    u += 0x7fffu + ((u >> 16) & 1u);
    return (ushort)(u >> 16);
}
__device__ __forceinline__ float bf2f(ushort h) {
    return __uint_as_float(((uint)h) << 16);
}
__device__ __forceinline__ ushort4 pack4bf(float a, float b, float c, float d) {
    union { __bf16 h[4]; ushort4 u; } p;
    p.h[0] = (__bf16)a; p.h[1] = (__bf16)b; p.h[2] = (__bf16)c; p.h[3] = (__bf16)d;
    return p.u;
}

#define GLD16(gsrc, ldst)                                                         \
    __builtin_amdgcn_global_load_lds(                                             \
        (const __attribute__((address_space(1))) unsigned int*)(gsrc),            \
        (__attribute__((address_space(3))) unsigned int*)(ldst), 16, 0, 0)

// Q pre-scale: (1/sqrt(64)) * log2(e)  -> softmax in exp2 domain
#define QSCALE 0.1803368801111204f

// ---------------- prep: x fp32 -> bf16 (hi only) ----------------
__global__ __launch_bounds__(256) void split_x(const float* __restrict__ in,
                                               ushort* __restrict__ oh, int n4) {
    int i = blockIdx.x * 256 + threadIdx.x;
    const int stride = gridDim.x * 256;
    for (; i < n4; i += stride) {
        const float4 v = reinterpret_cast<const float4*>(in)[i];
        ushort4 h;
        h.x = f2bf(v.x); h.y = f2bf(v.y); h.z = f2bf(v.z); h.w = f2bf(v.w);
        reinterpret_cast<ushort4*>(oh)[i] = h;
    }
}

// ---------------- prep: W^T; z<3 -> combined QKV hi; z==3 -> Wo hi/lo ----------------
__global__ __launch_bounds__(256) void tsplit_w(const float* __restrict__ Wq,
                                                const float* __restrict__ Wk,
                                                const float* __restrict__ Wv,
                                                const float* __restrict__ Wo,
                                                ushort* __restrict__ wtc,
                                                ushort* __restrict__ woh,
                                                ushort* __restrict__ wol) {
    const int z = blockIdx.z;
    const float* W = (z == 0) ? Wq : (z == 1) ? Wk : (z == 2) ? Wv : Wo;
    __shared__ float T[64][68];
    const int t = threadIdx.x;
    const int k0 = blockIdx.y * 64, n0 = blockIdx.x * 64;
    {
        const int r = t >> 2, c0 = (t & 3) * 16;
        #pragma unroll
        for (int j = 0; j < 4; ++j)
            *reinterpret_cast<float4*>(&T[r][c0 + j * 4]) =
                *reinterpret_cast<const float4*>(&W[(size_t)(k0 + r) * DMODEL + n0 + c0 + j * 4]);
    }
    __syncthreads();
    const int nl = t >> 2, kq = t & 3;
    if (z < 3) {
        ushort hb[16];
        #pragma unroll
        for (int e = 0; e < 16; ++e) hb[e] = f2bf(T[kq * 16 + e][nl]);
        const size_t o = (size_t)(z * 1024 + n0 + nl) * DMODEL + k0 + kq * 16;
        *reinterpret_cast<uint4*>(&wtc[o]) = *reinterpret_cast<uint4*>(&hb[0]);
        *reinterpret_cast<uint4*>(&wtc[o + 8]) = *reinterpret_cast<uint4*>(&hb[8]);
    } else {
        ushort hb[16], lb[16];
        #pragma unroll
        for (int e = 0; e < 16; ++e) {
            const float v = T[kq * 16 + e][nl];
            const ushort h = f2bf(v);
            hb[e] = h; lb[e] = f2bf(v - bf2f(h));
        }
        const size_t o = (size_t)(n0 + nl) * DMODEL + k0 + kq * 16;
        *reinterpret_cast<uint4*>(&woh[o]) = *reinterpret_cast<uint4*>(&hb[0]);
        *reinterpret_cast<uint4*>(&woh[o + 8]) = *reinterpret_cast<uint4*>(&hb[8]);
        *reinterpret_cast<uint4*>(&wol[o]) = *reinterpret_cast<uint4*>(&lb[0]);
        *reinterpret_cast<uint4*>(&wol[o + 8]) = *reinterpret_cast<uint4*>(&lb[8]);
    }
}

// ---------------- fused QKV GEMM: single-pass bf16, 128x128 tile, BK=64 ----------------
__global__ __launch_bounds__(512) void gemm_qkv(const ushort* __restrict__ xh,
                                                const ushort* __restrict__ wtc,
                                                ushort* __restrict__ Qb,
                                                ushort* __restrict__ Kb,
                                                ushort* __restrict__ Vtb) {
    __shared__ ushort SH[17408];
    ushort* const Ah = SH;
    ushort* const Bh = SH + 8192;

    const int t = threadIdx.x, lane = t & 63, w = t >> 6;
    const int l = lane & 15, g = lane >> 4;
    const int wm = w >> 2, wn = w & 3;
    const int bm = blockIdx.y * 128, bn = blockIdx.x * 128;

    f32x4 acc[4][2];
    #pragma unroll
    for (int mt = 0; mt < 4; ++mt)
        #pragma unroll
        for (int nt = 0; nt < 2; ++nt) acc[mt][nt] = (f32x4){0.f, 0.f, 0.f, 0.f};

    for (int kt = 0; kt < DMODEL; kt += 64) {
        __syncthreads();
        #pragma unroll
        for (int i = 0; i < 4; ++i) {
            const int sid = w * 4 + i;
            const int c = sid & 15;
            const ushort* src = (sid < 16) ? xh : wtc;
            const int rb = (sid < 16) ? bm : bn;
            ushort* dst = ((sid < 16) ? Ah : Bh) + c * 512;
            const int row = c * 8 + (lane >> 3);
            const int sw = ((lane & 7) ^ (row & 7)) << 3;
            GLD16(src + (size_t)(rb + row) * DMODEL + kt + sw, dst);
        }
        __syncthreads();

        bf16x8 af[4][2], bf[2][2];
        #pragma unroll
        for (int mt = 0; mt < 4; ++mt)
            #pragma unroll
            for (int s = 0; s < 2; ++s) {
                const int m = wm * 64 + mt * 16 + l;
                af[mt][s] = *reinterpret_cast<const bf16x8*>(&Ah[m * 64 + (((g + 4 * s) ^ (m & 7)) << 3)]);
            }
        #pragma unroll
        for (int nt = 0; nt < 2; ++nt)
            #pragma unroll
            for (int s = 0; s < 2; ++s) {
                const int n = wn * 32 + nt * 16 + l;
                bf[nt][s] = *reinterpret_cast<const bf16x8*>(&Bh[n * 64 + (((g + 4 * s) ^ (n & 7)) << 3)]);
            }
        #pragma unroll
        for (int mt = 0; mt < 4; ++mt)
            #pragma unroll
            for (int nt = 0; nt < 2; ++nt)
                #pragma unroll
                for (int s = 0; s < 2; ++s)
                    acc[mt][nt] = __builtin_amdgcn_mfma_f32_16x16x32_bf16(af[mt][s], bf[nt][s], acc[mt][nt], 0, 0, 0);
    }

    const int mode = bn >> 10;
    if (mode == 0) {
        #pragma unroll
        for (int mt = 0; mt < 4; ++mt)
            #pragma unroll
            for (int nt = 0; nt < 2; ++nt)
                #pragma unroll
                for (int r = 0; r < 4; ++r) {
                    const int row = bm + wm * 64 + mt * 16 + g * 4 + r;
                    const int col = bn + wn * 32 + nt * 16 + l;
                    Qb[(size_t)row * DMODEL + col] = f2bf(acc[mt][nt][r] * QSCALE);
                }
    } else if (mode == 1) {
        #pragma unroll
        for (int mt = 0; mt < 4; ++mt)
            #pragma unroll
            for (int nt = 0; nt < 2; ++nt)
                #pragma unroll
                for (int r = 0; r < 4; ++r) {
                    const int row = bm + wm * 64 + mt * 16 + g * 4 + r;
                    const int col = (bn - 1024) + wn * 32 + nt * 16 + l;
                    Kb[(size_t)row * DMODEL + col] = f2bf(acc[mt][nt][r]);
                }
    } else {
        __syncthreads();
        ushort* VtL = SH;   // [128 d][136 key]
        #pragma unroll
        for (int mt = 0; mt < 4; ++mt)
            #pragma unroll
            for (int nt = 0; nt < 2; ++nt)
                #pragma unroll
                for (int r = 0; r < 4; ++r) {
                    const int dl = wn * 32 + nt * 16 + l;
                    const int kl = wm * 64 + mt * 16 + g * 4 + r;
                    VtL[dl * 136 + kl] = f2bf(acc[mt][nt][r]);
                }
        __syncthreads();
        const int dl = t >> 2, kq = t & 3;
        const int b = bm >> 11;
        const int row = b * 1024 + (bn - 2048) + dl;
        const int key0 = bm & 2047;
        const size_t o = (size_t)row * SEQ + key0 + kq * 32;
        #pragma unroll
        for (int j = 0; j < 4; ++j)
            *reinterpret_cast<uint4*>(&Vtb[o + j * 8]) =
                *reinterpret_cast<uint4*>(&VtL[dl * 136 + kq * 32 + j * 8]);
    }
}

// ---------------- attention: paired tiles per wave, pipelined K/V, no barriers ----------------
// Block = 256 thr (4 waves). Wave w owns 16 rows of tile bx (set 0) and 16 rows
// of tile 31-bx (set 1); both sets share each chunk's K/V register fragments.
// All 512 blocks do identical work (33 chunk-sets).
#define LDP 72

__global__ __launch_bounds__(256, 2) void attn(const ushort* __restrict__ Q,
                                               const ushort* __restrict__ K,
                                               const ushort* __restrict__ Vt,
                                               ushort* __restrict__ ATh,
                                               ushort* __restrict__ ATl) {
    __shared__ ushort Pl[128 * LDP];   // wave-private rows

    const int t = threadIdx.x, lane = t & 63, w = t >> 6;
    const int l = lane & 15, g = lane >> 4;
    const int bx = blockIdx.x;                    // 0..15
    const int tA = bx, tB = 31 - bx;
    const int bh = blockIdx.y, b = bh >> 4, h = bh & 15;
    const size_t kbase = (size_t)b * SEQ * DMODEL + h * 64;
    const size_t vbase = (size_t)bh * 64 * SEQ;
    const int qrow0[2] = {tA * 64 + w * 16, tB * 64 + w * 16};
    const int nchA = tA + 1, nchB = tB + 1;       // nchA <= 16 < nchB

    // Q B-operand frags (col=q=lane&15, k=d=32s+8g+e) for both sets
    bf16x8 qf[2][2];
    #pragma unroll
    for (int qs = 0; qs < 2; ++qs) {
        const size_t qo = (size_t)(b * SEQ + qrow0[qs] + l) * DMODEL + h * 64 + 8 * g;
        qf[qs][0] = *reinterpret_cast<const bf16x8*>(&Q[qo]);
        qf[qs][1] = *reinterpret_cast<const bf16x8*>(&Q[qo + 32]);
    }

    f32x4 accO[2][4];
    #pragma unroll
    for (int qs = 0; qs < 2; ++qs)
        #pragma unroll
        for (int dt = 0; dt < 4; ++dt) accO[qs][dt] = (f32x4){0.f, 0.f, 0.f, 0.f};
    float m_i[2] = {-INFINITY, -INFINITY}, l_i[2] = {0.f, 0.f};

    bf16x8 kf[4][2], vf[4][2];

    // prologue: issue K(0)
    #pragma unroll
    for (int nt = 0; nt < 4; ++nt) {
        const size_t ko = kbase + (size_t)(nt * 16 + l) * DMODEL + 8 * g;
        kf[nt][0] = *reinterpret_cast<const bf16x8*>(&K[ko]);
        kf[nt][1] = *reinterpret_cast<const bf16x8*>(&K[ko + 32]);
    }

    for (int kc = 0; kc < nchB; ++kc) {
        const int k0 = kc * 64;
        const bool doA = (kc < nchA);

        // issue V(kc) early — consumed after softmax
        #pragma unroll
        for (int dt = 0; dt < 4; ++dt) {
            const size_t vo = vbase + (size_t)(dt * 16 + l) * SEQ + k0 + 8 * g;
            vf[dt][0] = *reinterpret_cast<const bf16x8*>(&Vt[vo]);
            vf[dt][1] = *reinterpret_cast<const bf16x8*>(&Vt[vo + 32]);
        }

        // swapped QK^T: sc[qs][nt][r] = score[key=k0+16nt+4g+r][q=qrow0+l]
        f32x4 sc[2][4];
        #pragma unroll
        for (int nt = 0; nt < 4; ++nt) {
            f32x4 z = (f32x4){0.f, 0.f, 0.f, 0.f};
            z = __builtin_amdgcn_mfma_f32_16x16x32_bf16(kf[nt][0], qf[1][0], z, 0, 0, 0);
            z = __builtin_amdgcn_mfma_f32_16x16x32_bf16(kf[nt][1], qf[1][1], z, 0, 0, 0);
            sc[1][nt] = z;
        }
        if (doA) {
            #pragma unroll
            for (int nt = 0; nt < 4; ++nt) {
                f32x4 z = (f32x4){0.f, 0.f, 0.f, 0.f};
                z = __builtin_amdgcn_mfma_f32_16x16x32_bf16(kf[nt][0], qf[0][0], z, 0, 0, 0);
                z = __builtin_amdgcn_mfma_f32_16x16x32_bf16(kf[nt][1], qf[0][1], z, 0, 0, 0);
                sc[0][nt] = z;
            }
        }

        // prefetch next chunk's K (kf consumed above; WAR ok, hides under softmax+PV)
        if (kc + 1 < nchB) {
            const int kn = k0 + 64;
            #pragma unroll
            for (int nt = 0; nt < 4; ++nt) {
                const size_t ko = kbase + (size_t)(kn + nt * 16 + l) * DMODEL + 8 * g;
                kf[nt][0] = *reinterpret_cast<const bf16x8*>(&K[ko]);
                kf[nt][1] = *reinterpret_cast<const bf16x8*>(&K[ko + 32]);
            }
        }

        // causal mask on each set's diagonal chunk
        #pragma unroll
        for (int qs = 0; qs < 2; ++qs) {
            if (kc == ((qs == 0) ? nchA : nchB) - 1) {
                const int qg = qrow0[qs] + l;
                #pragma unroll
                for (int nt = 0; nt < 4; ++nt)
                    #pragma unroll
                    for (int r = 0; r < 4; ++r)
                        if (k0 + nt * 16 + g * 4 + r > qg) sc[qs][nt][r] = -INFINITY;
            }
        }

        // online softmax (exp2 domain) + P->LDS, per active set
        #pragma unroll
        for (int qs = 0; qs < 2; ++qs) {
            if (qs == 0 && !doA) continue;
            float mc = sc[qs][0][0];
            #pragma unroll
            for (int nt = 0; nt < 4; ++nt)
                #pragma unroll
                for (int r = 0; r < 4; ++r) mc = fmaxf(mc, sc[qs][nt][r]);
            mc = fmaxf(mc, __shfl_xor(mc, 16, 64));
            mc = fmaxf(mc, __shfl_xor(mc, 32, 64));

            if (__any(mc > m_i[qs] + 8.f)) {          // defer-max rescale
                const float mn = fmaxf(m_i[qs], mc);
                const float al = exp2f(m_i[qs] - mn);
                m_i[qs] = mn;
                l_i[qs] *= al;
                #pragma unroll
                for (int r = 0; r < 4; ++r) {
                    const float ar = __shfl(al, 4 * g + r, 64);
                    #pragma unroll
                    for (int dt = 0; dt < 4; ++dt) accO[qs][dt][r] *= ar;
                }
            }

            float rs = 0.f;
            #pragma unroll
            for (int nt = 0; nt < 4; ++nt)
                #pragma unroll
                for (int r = 0; r < 4; ++r) {
                    const float p = exp2f(sc[qs][nt][r] - m_i[qs]);
                    sc[qs][nt][r] = p;
                    rs += p;
                }
            rs += __shfl_xor(rs, 16, 64);
            rs += __shfl_xor(rs, 32, 64);
            l_i[qs] += rs;

            const int prow = w * 32 + qs * 16 + l;
            #pragma unroll
            for (int nt = 0; nt < 4; ++nt)
                *reinterpret_cast<ushort4*>(&Pl[prow * LDP + nt * 16 + 4 * g]) =
                    pack4bf(sc[qs][nt][0], sc[qs][nt][1], sc[qs][nt][2], sc[qs][nt][3]);
        }

        // PV (waits V; next-K still in flight)
        #pragma unroll
        for (int qs = 0; qs < 2; ++qs) {
            if (qs == 0 && !doA) continue;
            bf16x8 pf[2];
            const int prow = w * 32 + qs * 16 + l;
            pf[0] = *reinterpret_cast<const bf16x8*>(&Pl[prow * LDP + 8 * g]);
            pf[1] = *reinterpret_cast<const bf16x8*>(&Pl[prow * LDP + 32 + 8 * g]);
            #pragma unroll
            for (int dt = 0; dt < 4; ++dt) {
                accO[qs][dt] = __builtin_amdgcn_mfma_f32_16x16x32_bf16(pf[0], vf[dt][0], accO[qs][dt], 0, 0, 0);
                accO[qs][dt] = __builtin_amdgcn_mfma_f32_16x16x32_bf16(pf[1], vf[dt][1], accO[qs][dt], 0, 0, 0);
            }
        }
    }

    // epilogue: normalize, emit attended hi/lo bf16
    #pragma unroll
    for (int qs = 0; qs < 2; ++qs) {
        #pragma unroll
        for (int r = 0; r < 4; ++r) {
            const float lr = __shfl(l_i[qs], 4 * g + r, 64);
            const float inv = 1.f / lr;
            const size_t row = (size_t)(b * SEQ + qrow0[qs] + g * 4 + r) * DMODEL + h * 64;
            #pragma unroll
            for (int dt = 0; dt < 4; ++dt) {
                const float val = accO[qs][dt][r] * inv;
                const ushort hh = f2bf(val);
                ATh[row + dt * 16 + l] = hh;
                ATl[row + dt * 16 + l] = f2bf(val - bf2f(hh));
            }
        }
    }
}

// ---------------- out GEMM: 3-pass hi/lo, 128x64 tile, BK=64, fp32 out ----------------
__global__ __launch_bounds__(512) void gemm_o(const ushort* __restrict__ Ahg,
                                              const ushort* __restrict__ Alg,
                                              const ushort* __restrict__ Bhg,
                                              const ushort* __restrict__ Blg,
                                              float* __restrict__ C) {
    __shared__ ushort SH[24576];
    ushort* const Ah = SH;
    ushort* const Al = SH + 8192;
    ushort* const Bh = SH + 16384;
    ushort* const Bl = SH + 20480;

    const int t = threadIdx.x, lane = t & 63, w = t >> 6;
    const int l = lane & 15, g = lane >> 4;
    const int wm = w >> 1, wn = w & 1;
    const int bm = blockIdx.y * 128, bn = blockIdx.x * 64;

    f32x4 acc[2][2];
    #pragma unroll
    for (int mt = 0; mt < 2; ++mt)
        #pragma unroll
        for (int nt = 0; nt < 2; ++nt) acc[mt][nt] = (f32x4){0.f, 0.f, 0.f, 0.f};

    for (int kt = 0; kt < DMODEL; kt += 64) {
        __syncthreads();
        #pragma unroll
        for (int i = 0; i < 6; ++i) {
            const int sid = w * 6 + i;
            const ushort* src; ushort* dst; int rb, c;
            if (sid < 16)      { src = Ahg; dst = Ah; rb = bm; c = sid; }
            else if (sid < 32) { src = Alg; dst = Al; rb = bm; c = sid - 16; }
            else if (sid < 40) { src = Bhg; dst = Bh; rb = bn; c = sid - 32; }
            else               { src = Blg; dst = Bl; rb = bn; c = sid - 40; }
            const int row = c * 8 + (lane >> 3);
            const int sw = ((lane & 7) ^ (row & 7)) << 3;
            GLD16(src + (size_t)(rb + row) * DMODEL + kt + sw, dst + c * 512);
        }
        __syncthreads();

        bf16x8 ah[2][2], al[2][2], bhf[2][2], blf[2][2];
        #pragma unroll
        for (int mt = 0; mt < 2; ++mt)
            #pragma unroll
            for (int s = 0; s < 2; ++s) {
                const int m = wm * 32 + mt * 16 + l;
                const int off = m * 64 + (((g + 4 * s) ^ (m & 7)) << 3);
                ah[mt][s] = *reinterpret_cast<const bf16x8*>(&Ah[off]);
                al[mt][s] = *reinterpret_cast<const bf16x8*>(&Al[off]);
            }
        #pragma unroll
        for (int nt = 0; nt < 2; ++nt)
            #pragma unroll
            for (int s = 0; s < 2; ++s) {
                const int n = wn * 32 + nt * 16 + l;
                const int off = n * 64 + (((g + 4 * s) ^ (n & 7)) << 3);
                bhf[nt][s] = *reinterpret_cast<const bf16x8*>(&Bh[off]);
                blf[nt][s] = *reinterpret_cast<const bf16x8*>(&Bl[off]);
            }
        #pragma unroll
        for (int mt = 0; mt < 2; ++mt)
            #pragma unroll
            for (int nt = 0; nt < 2; ++nt)
                #pragma unroll
                for (int s = 0; s < 2; ++s) {
                    acc[mt][nt] = __builtin_amdgcn_mfma_f32_16x16x32_bf16(ah[mt][s], bhf[nt][s], acc[mt][nt], 0, 0, 0);
                    acc[mt][nt] = __builtin_amdgcn_mfma_f32_16x16x32_bf16(ah[mt][s], blf[nt][s], acc[mt][nt], 0, 0, 0);
                    acc[mt][nt] = __builtin_amdgcn_mfma_f32_16x16x32_bf16(al[mt][s], bhf[nt][s], acc[mt][nt], 0, 0, 0);
                }
    }

    #pragma unroll
    for (int mt = 0; mt < 2; ++mt)
        #pragma unroll
        for (int nt = 0; nt < 2; ++nt)
            #pragma unroll
            for (int r = 0; r < 4; ++r) {
                const int row = bm + wm * 32 + mt * 16 + g * 4 + r;
                const int col = bn + wn * 32 + nt * 16 + l;
                C[(size_t)row * DMODEL + col] = acc[mt][nt][r];
            }
}

// ---------------- launch ----------------
extern "C" void kernel_launch(void* const* d_in, const int* in_sizes, int n_in,
                              void* d_out, int out_size, void* d_ws, size_t ws_size,
                              hipStream_t stream) {
    const float* x  = (const float*)d_in[0];
    const float* Wq = (const float*)d_in[1];
    const float* Wk = (const float*)d_in[2];
    const float* Wv = (const float*)d_in[3];
    const float* Wo = (const float*)d_in[4];
    float* out = (float*)d_out;

    char* ws = (char*)d_ws;
    const size_t MB = 1024 * 1024;
    ushort* xh  = (ushort*)(ws);              // 8 MB  (aliased as ATh after QKV gemm)
    ushort* ath = xh;
    ushort* atl = (ushort*)(ws + 8 * MB);     // 8 MB
    ushort* wtc = (ushort*)(ws + 16 * MB);    // 6 MB  [3072][1024]
    ushort* woh = (ushort*)(ws + 22 * MB);    // 2 MB
    ushort* wol = (ushort*)(ws + 24 * MB);    // 2 MB
    ushort* Qb  = (ushort*)(ws + 26 * MB);    // 8 MB
    ushort* Kb  = (ushort*)(ws + 34 * MB);    // 8 MB
    ushort* Vtb = (ushort*)(ws + 42 * MB);    // 8 MB

    split_x<<<1024, 256, 0, stream>>>(x, xh, MROWS * DMODEL / 4);
    tsplit_w<<<dim3(16, 16, 4), 256, 0, stream>>>(Wq, Wk, Wv, Wo, wtc, woh, wol);

    gemm_qkv<<<dim3(24, 32), 512, 0, stream>>>(xh, wtc, Qb, Kb, Vtb);

    attn<<<dim3(16, 32), 256, 0, stream>>>(Qb, Kb, Vtb, ath, atl);

    gemm_o<<<dim3(16, 32), 512, 0, stream>>>(ath, atl, woh, wol, out);
}